// Round 12
// baseline (2213.688 us; speedup 1.0000x reference)
//
#include <hip/hip_runtime.h>
#include <math.h>

#define NDOF 4
#define NB   512
#define NT   64
#define ND   256
#define NS   1024           // NDOF*ND

#define NRT  4
#define GRID 128

typedef __attribute__((ext_vector_type(8))) __bf16 bf16x8;
typedef __attribute__((ext_vector_type(4))) float  f32x4;

__device__ __forceinline__ void gll16(const void* g, void* l) {
    __builtin_amdgcn_global_load_lds(
        (const __attribute__((address_space(1))) unsigned int*)g,
        (__attribute__((address_space(3))) unsigned int*)l, 16, 0, 0);
}

__device__ __forceinline__ float sig_(float x) { return 1.0f / (1.0f + __expf(-x)); }
__device__ __forceinline__ float tanh_(float x) {
    float e = __expf(-2.0f * fabsf(x));
    float t = (1.0f - e) / (1.0f + e);
    return copysignf(t, x);
}

// coalesced coherent store: 16B write-through to MALL
__device__ __forceinline__ void store16_dev(__bf16* p, bf16x8 v) {
    asm volatile("global_store_dwordx4 %0, %1, off sc0 sc1" :: "v"(p), "v"(v) : "memory");
}

__device__ __forceinline__ void waitv0() {
    asm volatile("s_waitcnt vmcnt(0)" ::: "memory");
    __builtin_amdgcn_sched_barrier(0);
}
__device__ __forceinline__ void waitv8() {
    asm volatile("s_waitcnt vmcnt(8)" ::: "memory");
    __builtin_amdgcn_sched_barrier(0);
}
__device__ __forceinline__ void waitv16() {
    asm volatile("s_waitcnt vmcnt(16)" ::: "memory");
    __builtin_amdgcn_sched_barrier(0);
}

// raw block barrier: does NOT drain vmcnt (loads stay in flight across it).
__device__ __forceinline__ void block_bar() {
    __builtin_amdgcn_sched_barrier(0);
    asm volatile("s_waitcnt lgkmcnt(0)\n\ts_barrier" ::: "memory");
    __builtin_amdgcn_sched_barrier(0);
}

// coherent flag read: plain MALL load (no line ownership)
__device__ __forceinline__ unsigned gen_load(const unsigned* p) {
    unsigned v;
    asm volatile("global_load_dword %0, %1, off sc0 sc1\n\ts_waitcnt vmcnt(0)"
                 : "=v"(v) : "v"(p) : "memory");
    return v;
}

// -------- split arrive/poll group barriers --------
struct __align__(64) Bar { unsigned cnt; unsigned gen; unsigned pad[14]; };

__device__ __forceinline__ void arrive_only(Bar* b, unsigned n, unsigned e) {
    unsigned prev = __hip_atomic_fetch_add(&b->cnt, 1u, __ATOMIC_RELAXED, __HIP_MEMORY_SCOPE_AGENT);
    if (prev == e * n - 1u)
        __hip_atomic_fetch_add(&b->gen, 1u, __ATOMIC_RELAXED, __HIP_MEMORY_SCOPE_AGENT);
}
__device__ __forceinline__ void poll_only(Bar* b, unsigned e) {
    unsigned spins = 0;
    while (gen_load(&b->gen) < e) {
        __builtin_amdgcn_s_sleep(1);
        if (++spins > (1u << 17)) break;   // failsafe: fail loud, never hang
    }
}

struct Params {
    const __bf16* xbf;
    const __bf16* wT1;
    const __bf16* wT2;
    const float *b1u, *b1f, *b1o, *b1c;
    const float *b2u, *b2f, *b2o, *b2c;
    const __bf16* hInit;   // 1 MB zeros [512][1024]
    __bf16* ring;          // [NT*2] slots of [512][1024] bf16 (1 MB each)
    float*  out;
    Bar*    bars;          // [0..3]=bar32A[rt]; [4+g]=bar8A; [20+g]=bar8B
};

// ---- pair staging. rot permutes the K order (pair p -> k ((p+rot)&mask)*64).
__device__ __forceinline__ void issueB(bf16x8* smem, const __bf16* wrow,
                                       int pair, int rot, int mask, int row, int kgb) {
    const int bb = 4096 + (pair & 3) * 1024;
    const int k0 = ((pair + rot) & mask) * 64;
    #pragma unroll
    for (int i = 0; i < 4; ++i) {
        const int kg = kgb + 2 * i;
        gll16(wrow + k0 + kg * 8, &smem[bb + kg * 128 + row]);
    }
}
template<int XIT>
__device__ __forceinline__ void issueA(bf16x8* smem, const __bf16* ax,
                                       const __bf16* ah, int pair, int rot, int mask,
                                       int row, int kgb) {
    const int bb = (pair & 3) * 1024;
    const __bf16* base;
    if (XIT > 0 && pair < XIT) base = ax + (size_t)row * ND + pair * 64;   // x part (rot=0)
    else base = ah + (size_t)row * NS + (((pair + rot) & mask) * 64 - XIT * 64);
    #pragma unroll
    for (int i = 0; i < 4; ++i) {
        const int kg = kgb + 2 * i;
        gll16(base + kg * 8, &smem[bb + kg * 128 + row]);
    }
}

// ---- GEMM core, 2 pairs per segment, rolled loop (I$-resident).
// Pairs 0,1 pre-issued by caller. Per segment: vmcnt(0) [this segment's 2
// pairs landed; nothing else in flight], one s_barrier, issue next 2 pairs
// (into the buffer-pair freed last segment), consume 2 pairs (4 MFMA subs).
// gateBar (if set) polled at s==1, before the first gated pair issue.
template<int NIT, int XIT>
__device__ __forceinline__ void gemm_seg(bf16x8* smem,
    const __bf16* ax, const __bf16* ah, const __bf16* wrow, int rot,
    Bar* gateBar, unsigned gateE,
    f32x4 (&acc)[4][4], int lane, int wr, int ws, int row, int kgb, int tid)
{
    constexpr int NSEG = NIT / 2;
    #pragma unroll 1
    for (int s = 0; s < NSEG; ++s) {
        waitv0();
        block_bar();
        if (s == 1 && gateBar != nullptr) {
            if (tid == 0) poll_only(gateBar, gateE);
            block_bar();
        }
        if (s + 1 < NSEG) {
            issueB(smem, wrow, 2 * s + 2, rot, NIT - 1, row, kgb);
            issueB(smem, wrow, 2 * s + 3, rot, NIT - 1, row, kgb);
            issueA<XIT>(smem, ax, ah, 2 * s + 2, rot, NIT - 1, row, kgb);
            issueA<XIT>(smem, ax, ah, 2 * s + 3, rot, NIT - 1, row, kgb);
        }
        #pragma unroll
        for (int q = 0; q < 2; ++q) {
            const int bb = ((2 * s + q) & 3) * 1024;
            #pragma unroll
            for (int sub = 0; sub < 2; ++sub) {
                const int kq = sub * 4 + (lane >> 4);
                bf16x8 a[4], b[4];
                #pragma unroll
                for (int mI = 0; mI < 4; ++mI)
                    a[mI] = smem[bb + kq * 128 + wr + mI * 16 + (lane & 15)];
                #pragma unroll
                for (int g = 0; g < 4; ++g)
                    b[g] = smem[4096 + bb + kq * 128 + g * 32 + ws * 16 + (lane & 15)];
                #pragma unroll
                for (int mI = 0; mI < 4; ++mI)
                    #pragma unroll
                    for (int g = 0; g < 4; ++g)
                        acc[mI][g] = __builtin_amdgcn_mfma_f32_16x16x32_bf16(a[mI], b[g], acc[mI][g], 0, 0, 0);
            }
        }
    }
}

// ---- LSTM epilogue: compute gates, update m_reg, stage h (bf16) into LDS ----
__device__ __forceinline__ void epi_stage(const f32x4 (&acc)[4][4], float (&m_reg)[16],
    float bu, float bf_, float bo, float bc,
    char* stg, int wrL, int colq)
{
    #pragma unroll
    for (int mI = 0; mI < 4; ++mI) {
        #pragma unroll
        for (int r = 0; r < 4; ++r) {
            const int rowL = wrL + mI * 16 + r;   // local row 0..127
            const float gu = sig_(acc[mI][0][r] + bu);
            const float gf = sig_(acc[mI][1][r] + bf_);
            const float go = sig_(acc[mI][2][r] + bo);
            const float gc = tanh_(acc[mI][3][r] + bc);
            float& m = m_reg[mI * 4 + r];
            m = gf * m + gu * gc;
            ((__bf16*)(stg + rowL * 80))[colq] = (__bf16)tanh_(go * m);
        }
    }
}

// coalesced flush of the staged 128x32 bf16 tile: 2 x 16B stores per thread.
__device__ __forceinline__ void flush_h(char* stg, __bf16* hbase, int r0,
                                        int scolBase, int tid)
{
    #pragma unroll
    for (int k = 0; k < 2; ++k) {
        const int c = tid + 256 * k;          // 0..511
        const int rowL = c >> 2;
        const int off  = c & 3;               // 4 x 16B chunks per row
        bf16x8 v = *(bf16x8*)(stg + rowL * 80 + off * 16);
        store16_dev(hbase + (size_t)(r0 + rowL) * NS + scolBase + off * 8, v);
    }
}

// final-step epilogue: stage h,m as f32 in (idle) pipeline LDS, coalesced out.
__device__ __forceinline__ void epi_last(const f32x4 (&acc)[4][4], float (&m_reg)[16],
    float bu, float bf_, float bo, float bc,
    char* hs, char* ms, int wrL, int colq)
{
    #pragma unroll
    for (int mI = 0; mI < 4; ++mI) {
        #pragma unroll
        for (int r = 0; r < 4; ++r) {
            const int rowL = wrL + mI * 16 + r;
            const float gu = sig_(acc[mI][0][r] + bu);
            const float gf = sig_(acc[mI][1][r] + bf_);
            const float go = sig_(acc[mI][2][r] + bo);
            const float gc = tanh_(acc[mI][3][r] + bc);
            float& m = m_reg[mI * 4 + r];
            m = gf * m + gu * gc;
            ((float*)(hs + rowL * 144))[colq] = tanh_(go * m);
            ((float*)(ms + rowL * 144))[colq] = m;
        }
    }
}

__global__ __launch_bounds__(256, 1)
void lstm_persistent(Params p)
{
    __shared__ bf16x8 smem[8832];   // 128KB pipeline + 10KB h staging
    char* stg = (char*)&smem[8192];

    const int tid  = threadIdx.x;
    const int lane = tid & 63;
    const int wv   = tid >> 6;
    const int wr   = (wv >> 1) * 64;
    const int ws   = wv & 1;

    // ---- XCD-aware work map (dispatch assigns bid -> XCD bid%8) ----
    const int xcd   = blockIdx.x & 7;
    const int local = blockIdx.x >> 3;            // 0..15
    const int dof   = xcd & 3;
    const int rt    = ((xcd >> 2) << 1) | (local >> 3);   // 0..3
    const int c0    = (local & 7) * 32;
    const int r0    = rt * 128;
    const int grp   = rt * 4 + dof;

    const int row  = tid & 127;
    const int kgb  = (tid >> 7) & 1;

    const int colq = ws * 16 + (lane & 15);       // 0..31 (block-local col)
    const int scol = dof * ND + c0 + colq;
    const int scolBase = dof * ND + c0;
    const int wrL  = wr + (lane >> 4) * 4;

    const int rowT = tid & 127;
    const int npT  = dof * 1024 + (rowT >> 5) * 256 + c0 + (rowT & 31);
    const __bf16* wrow1 = p.wT1 + (size_t)npT * 512;
    const __bf16* wrow2 = p.wT2 + (size_t)npT * 1024;

    const float b1u = p.b1u[scol], b1f = p.b1f[scol], b1o = p.b1o[scol], b1c = p.b1c[scol];
    const float b2u = p.b2u[scol], b2f = p.b2f[scol], b2o = p.b2o[scol], b2c = p.b2c[scol];

    float m_reg[16];
    #pragma unroll
    for (int i = 0; i < 16; ++i) m_reg[i] = 0.f;

    Bar* bar32A = &p.bars[rt];
    Bar* bar8A  = &p.bars[4 + grp];
    Bar* bar8B  = &p.bars[20 + grp];
    const int rot2 = dof * 4;   // phase-2 K rotation: own-dof h1 cols first

    auto slot = [&](int i) -> __bf16* { return p.ring + ((size_t)i << 19); };

    // kernel-start prologue: pairs 0,1 of t=0 phase-1 (B then A; both are x/w)
    {
        const __bf16* ax0 = p.xbf + ((size_t)(dof * NT) * NB + r0) * ND;
        issueB(smem, wrow1, 0, 0, 7, row, kgb);
        issueB(smem, wrow1, 1, 0, 7, row, kgb);
        issueA<4>(smem, ax0, nullptr, 0, 0, 7, row, kgb);
        issueA<4>(smem, ax0, nullptr, 1, 0, 7, row, kgb);
    }

    #pragma unroll 1
    for (int t = 0; t < NT; ++t) {
        const __bf16* ax  = p.xbf + ((size_t)(dof * NT + t) * NB + r0) * ND;
        const __bf16* ah1 = (t == 0 ? p.hInit : slot(2 * t - 1)) + (size_t)r0 * NS + dof * ND;
        __bf16* h1out = slot(2 * t);
        const __bf16* ah2 = slot(2 * t) + (size_t)r0 * NS;
        __bf16* h2out = slot(2 * t + 1);

        // ---------- phase 1: per-dof cell, K=512 = [x_t | h_own] ----------
        f32x4 acc[4][4];
        #pragma unroll
        for (int mI = 0; mI < 4; ++mI)
            #pragma unroll
            for (int g = 0; g < 4; ++g) acc[mI][g] = (f32x4){0.f, 0.f, 0.f, 0.f};

        gemm_seg<8, 4>(smem, ax, ah1, wrow1, 0, bar8B, (unsigned)t,
                       acc, lane, wr, ws, row, kgb, tid);

        // ---- transition A ----
        epi_stage(acc, m_reg, b1u, b1f, b1o, b1c, stg, wrL, colq);
        block_bar();                      // staging visible block-wide
        flush_h(stg, h1out, r0, scolBase, tid);      // 2 coalesced stores (oldest)
        issueB(smem, wrow2, 0, rot2, 15, row, kgb);  // 8 B2-prologue loads
        issueB(smem, wrow2, 1, rot2, 15, row, kgb);
        waitv8();                         // retires the 2 stores, loads in flight
        block_bar();
        if (tid == 0) {
            arrive_only(bar8A, 8, (unsigned)(t + 1));
            arrive_only(bar32A, 32, (unsigned)(t + 1));
            poll_only(bar8A, (unsigned)(t + 1));
        }
        block_bar();
        issueA<0>(smem, nullptr, ah2, 0, rot2, 15, row, kgb);
        issueA<0>(smem, nullptr, ah2, 1, rot2, 15, row, kgb);

        // ---------- phase 2: grid coupling, K=1024 (own dof first) ----------
        #pragma unroll
        for (int mI = 0; mI < 4; ++mI)
            #pragma unroll
            for (int g = 0; g < 4; ++g) acc[mI][g] = (f32x4){0.f, 0.f, 0.f, 0.f};

        gemm_seg<16, 0>(smem, nullptr, ah2, wrow2, rot2, bar32A, (unsigned)(t + 1),
                        acc, lane, wr, ws, row, kgb, tid);

        if (t + 1 < NT) {
            // ---- transition B ----
            epi_stage(acc, m_reg, b2u, b2f, b2o, b2c, stg, wrL, colq);
            block_bar();
            flush_h(stg, h2out, r0, scolBase, tid);  // 2 stores (oldest)
            const __bf16* axn = p.xbf + ((size_t)(dof * NT + t + 1) * NB + r0) * ND;
            issueB(smem, wrow1, 0, 0, 7, row, kgb);  // next phase-1 pairs 0,1 (x/w only)
            issueB(smem, wrow1, 1, 0, 7, row, kgb);
            issueA<4>(smem, axn, nullptr, 0, 0, 7, row, kgb);
            issueA<4>(smem, axn, nullptr, 1, 0, 7, row, kgb);
            waitv16();                    // retires the 2 stores; 16 loads in flight
            block_bar();
            if (tid == 0) arrive_only(bar8B, 8, (unsigned)(t + 1));
            // next phase-1 gates on bar8B at its s==1
        } else {
            // ---- final epilogue: coalesced f32 h+m into d_out ----
            block_bar();                  // pipeline LDS now reusable
            char* hs = (char*)smem;           // [128][144B] f32 h
            char* ms = (char*)smem + 36864;   // [128][144B] f32 m
            epi_last(acc, m_reg, b2u, b2f, b2o, b2c, hs, ms, wrL, colq);
            block_bar();
            #pragma unroll
            for (int k = 0; k < 4; ++k) {
                const int c = tid + 256 * k;      // 0..1023
                const int rowL = c >> 3;
                const int off  = c & 7;           // 8 x 16B per 128B row
                const size_t gi = ((size_t)dof * NB + r0 + rowL) * ND + c0 + off * 4;
                *(f32x4*)(p.out + gi) = *(f32x4*)(hs + rowL * 144 + off * 16);
                *(f32x4*)(p.out + (size_t)NDOF * NB * ND + gi) = *(f32x4*)(ms + rowL * 144 + off * 16);
            }
        }
    }
}

// ---- one-time prep: x[d][b][t][:] fp32 -> xbf[d][t][b][:] bf16 ----
__global__ __launch_bounds__(256)
void convert_x(const float* __restrict__ x, __bf16* __restrict__ xbf)
{
    const int id  = blockIdx.x * 256 + threadIdx.x;
    const int d0  = (id & 31) * 8;
    const int t   = (id >> 5) & 63;
    const int b   = (id >> 11) & 511;
    const int dof = id >> 20;
    const float* s = x + (((size_t)dof * NB + b) * NT + t) * ND + d0;
    const float4 v0 = *(const float4*)s;
    const float4 v1 = *(const float4*)(s + 4);
    bf16x8 o;
    o[0] = (__bf16)v0.x; o[1] = (__bf16)v0.y; o[2] = (__bf16)v0.z; o[3] = (__bf16)v0.w;
    o[4] = (__bf16)v1.x; o[5] = (__bf16)v1.y; o[6] = (__bf16)v1.z; o[7] = (__bf16)v1.w;
    *(bf16x8*)(xbf + (((size_t)dof * NT + t) * NB + b) * ND + d0) = o;
}

// ---- one-time prep: weights -> bf16 wT[n'][k], n' = dof*1024 + g*256 + col ----
__global__ __launch_bounds__(256)
void transpose_weights(const float* __restrict__ wu, const float* __restrict__ wf,
                       const float* __restrict__ wo, const float* __restrict__ wcp,
                       const float* __restrict__ gwu, const float* __restrict__ gwf,
                       const float* __restrict__ gwo, const float* __restrict__ gwc,
                       __bf16* __restrict__ wT1, __bf16* __restrict__ wT2)
{
    int id = blockIdx.x * 256 + threadIdx.x;
    const int C1 = 4096 * 64;
    int K, np, kc;
    const float *s0, *s1, *s2, *s3;
    __bf16* dst;
    if (id < C1) { K = 512;  np = id & 4095; kc = id >> 12; dst = wT1; s0 = wu;  s1 = wf;  s2 = wo;  s3 = wcp; }
    else { id -= C1; K = 1024; np = id & 4095; kc = id >> 12; dst = wT2; s0 = gwu; s1 = gwf; s2 = gwo; s3 = gwc; }
    const int dof = np >> 10, q = np & 1023, g = q >> 8, col = q & 255;
    const float* w = ((g == 0) ? s0 : (g == 1) ? s1 : (g == 2) ? s2 : s3)
                     + ((size_t)dof * K + kc * 8) * ND + col;
    bf16x8 o;
    #pragma unroll
    for (int j = 0; j < 8; ++j) o[j] = (__bf16)w[j * ND];
    *(bf16x8*)(dst + (size_t)np * K + kc * 8) = o;
}

extern "C" void kernel_launch(void* const* d_in, const int* in_sizes, int n_in,
                              void* d_out, int out_size, void* d_ws, size_t ws_size,
                              hipStream_t stream)
{
    const float* x   = (const float*)d_in[0];
    const float* wu  = (const float*)d_in[1];
    const float* wf  = (const float*)d_in[2];
    const float* wo  = (const float*)d_in[3];
    const float* wc  = (const float*)d_in[4];

    char* ws = (char*)d_ws;
    __bf16* wT1  = (__bf16*)ws;                        //   4 MB  [4096][512]
    __bf16* wT2  = (__bf16*)(ws + (4u  << 20));        //   8 MB  [4096][1024]
    __bf16* xbf  = (__bf16*)(ws + (12u << 20));        //  64 MB  [4][64][512][256]
    __bf16* hIn  = (__bf16*)(ws + (76u << 20));        //   1 MB  zeros
    Bar*    bars = (Bar*)  (ws + (78u << 20));         //   4 KB
    __bf16* ring = (__bf16*)(ws + (80u << 20));        // 128 MB  [NT*2][512][1024]

    convert_x<<<16384, 256, 0, stream>>>(x, xbf);
    transpose_weights<<<3072, 256, 0, stream>>>(
        wu, wf, wo, wc,
        (const float*)d_in[9], (const float*)d_in[10],
        (const float*)d_in[11], (const float*)d_in[12], wT1, wT2);
    // zero hInit + bars each call (deterministic across replays)
    hipMemsetAsync(ws + (76u << 20), 0, (2u << 20) + 4096, stream);

    Params p;
    p.xbf = xbf; p.wT1 = wT1; p.wT2 = wT2;
    p.b1u = (const float*)d_in[5];  p.b1f = (const float*)d_in[6];
    p.b1o = (const float*)d_in[7];  p.b1c = (const float*)d_in[8];
    p.b2u = (const float*)d_in[13]; p.b2f = (const float*)d_in[14];
    p.b2o = (const float*)d_in[15]; p.b2c = (const float*)d_in[16];
    p.hInit = hIn; p.ring = ring; p.out = (float*)d_out; p.bars = bars;

    lstm_persistent<<<dim3(GRID), dim3(256), 0, stream>>>(p);
}

// Round 13
// 1625.473 us; speedup vs baseline: 1.3619x; 1.3619x over previous
//
#include <hip/hip_runtime.h>
#include <math.h>

#define NDOF 4
#define NB   512
#define NT   64
#define ND   256
#define NS   1024           // NDOF*ND

// 256 blocks = 8 rt (64-row tiles) x 32 nt (4 gates x 32 cols), XCD-mapped.
#define GRID 256

typedef __attribute__((ext_vector_type(8))) __bf16 bf16x8;
typedef __attribute__((ext_vector_type(4))) float  f32x4;

__device__ __forceinline__ void gll16(const void* g, void* l) {
    __builtin_amdgcn_global_load_lds(
        (const __attribute__((address_space(1))) unsigned int*)g,
        (__attribute__((address_space(3))) unsigned int*)l, 16, 0, 0);
}

__device__ __forceinline__ float sig_(float x) { return 1.0f / (1.0f + __expf(-x)); }
__device__ __forceinline__ float tanh_(float x) {
    float e = __expf(-2.0f * fabsf(x));
    float t = (1.0f - e) / (1.0f + e);
    return copysignf(t, x);
}

// coalesced coherent store: 16B write-through to MALL
__device__ __forceinline__ void store16_dev(__bf16* p, bf16x8 v) {
    asm volatile("global_store_dwordx4 %0, %1, off sc0 sc1" :: "v"(p), "v"(v) : "memory");
}

__device__ __forceinline__ void waitv0() {
    asm volatile("s_waitcnt vmcnt(0)" ::: "memory");
    __builtin_amdgcn_sched_barrier(0);
}
__device__ __forceinline__ void waitv8() {
    asm volatile("s_waitcnt vmcnt(8)" ::: "memory");
    __builtin_amdgcn_sched_barrier(0);
}
__device__ __forceinline__ void waitv12() {
    asm volatile("s_waitcnt vmcnt(12)" ::: "memory");
    __builtin_amdgcn_sched_barrier(0);
}

// raw block barrier: does NOT drain vmcnt (loads stay in flight across it).
__device__ __forceinline__ void block_bar() {
    __builtin_amdgcn_sched_barrier(0);
    asm volatile("s_waitcnt lgkmcnt(0)\n\ts_barrier" ::: "memory");
    __builtin_amdgcn_sched_barrier(0);
}

// coherent flag read: plain MALL load (no line ownership)
__device__ __forceinline__ unsigned gen_load(const unsigned* p) {
    unsigned v;
    asm volatile("global_load_dword %0, %1, off sc0 sc1\n\ts_waitcnt vmcnt(0)"
                 : "=v"(v) : "v"(p) : "memory");
    return v;
}

// -------- split arrive/poll group barriers --------
struct __align__(64) Bar { unsigned cnt; unsigned gen; unsigned pad[14]; };

__device__ __forceinline__ void arrive_only(Bar* b, unsigned n, unsigned e) {
    unsigned prev = __hip_atomic_fetch_add(&b->cnt, 1u, __ATOMIC_RELAXED, __HIP_MEMORY_SCOPE_AGENT);
    if (prev == e * n - 1u)
        __hip_atomic_fetch_add(&b->gen, 1u, __ATOMIC_RELAXED, __HIP_MEMORY_SCOPE_AGENT);
}
__device__ __forceinline__ void poll_only(Bar* b, unsigned e) {
    unsigned spins = 0;
    while (gen_load(&b->gen) < e) {
        __builtin_amdgcn_s_sleep(1);
        if (++spins > (1u << 17)) break;   // failsafe: fail loud, never hang
    }
}

struct Params {
    const __bf16* xbf;
    const __bf16* wT1;
    const __bf16* wT2;
    const float *b1u, *b1f, *b1o, *b1c;
    const float *b2u, *b2f, *b2o, *b2c;
    const __bf16* hInit;   // 1 MB zeros [512][1024]
    __bf16* ring;          // [NT*2] slots of [512][1024] bf16 (1 MB each)
    float*  out;
    Bar*    bars;          // [0..7]=bar32A[rt]; [8+g]=bar8A; [40+g]=bar8B
};

// ---- pair staging. rot permutes the K order (pair p -> k ((p+rot)&mask)*64).
// LDS 16B-chunk units: A 4-deep [0,2048) (512/buf), B 4-deep [2048,6144) (1024/buf).
__device__ __forceinline__ void issueB(bf16x8* smem, const __bf16* wrow,
                                       int pair, int rot, int mask, int tid) {
    const int rowB = tid & 127;
    const int kgb  = (tid >> 7) & 1;
    const int bb = 2048 + (pair & 3) * 1024;
    const int k0 = ((pair + rot) & mask) * 64;
    #pragma unroll
    for (int i = 0; i < 4; ++i) {
        const int kg = kgb + 2 * i;
        gll16(wrow + k0 + kg * 8, &smem[bb + kg * 128 + rowB]);
    }
}
template<int XIT>
__device__ __forceinline__ void issueA(bf16x8* smem, const __bf16* ax,
                                       const __bf16* ah, int pair, int rot, int mask,
                                       int tid) {
    const int rowA = tid & 63;
    const int kga  = tid >> 6;            // 0..3
    const int bb = (pair & 3) * 512;
    const __bf16* base;
    if (XIT > 0 && pair < XIT) base = ax + (size_t)rowA * ND + pair * 64;   // x (rot=0)
    else base = ah + (size_t)rowA * NS + (((pair + rot) & mask) * 64 - XIT * 64);
    #pragma unroll
    for (int i = 0; i < 2; ++i) {
        const int kg = kga + 4 * i;
        gll16(base + kg * 8, &smem[bb + kg * 64 + rowA]);
    }
}

// ---- GEMM core: 2 pairs/segment, rolled loop. Pairs 0,1 pre-issued.
// Steady state: 12 loads in flight (2 pairs x (4 B + 2 A) per thread).
// Per segment: vmcnt(0) [both pairs landed], barrier, issue next 2 pairs,
// compute 2 pairs. gateBar polled at s==1 (before the first gated pair issue).
template<int NIT, int XIT>
__device__ __forceinline__ void gemm_seg(bf16x8* smem,
    const __bf16* ax, const __bf16* ah, const __bf16* wrow, int rot,
    Bar* gateBar, unsigned gateE,
    f32x4 (&acc)[2][4], int lane, int wr, int ws, int tid)
{
    constexpr int NSEG = NIT / 2;
    #pragma unroll 1
    for (int s = 0; s < NSEG; ++s) {
        waitv0();
        block_bar();
        if (s == 1 && gateBar != nullptr) {
            if (tid == 0) poll_only(gateBar, gateE);
            block_bar();
        }
        if (s + 1 < NSEG) {
            issueB(smem, wrow, 2 * s + 2, rot, NIT - 1, tid);
            issueB(smem, wrow, 2 * s + 3, rot, NIT - 1, tid);
            issueA<XIT>(smem, ax, ah, 2 * s + 2, rot, NIT - 1, tid);
            issueA<XIT>(smem, ax, ah, 2 * s + 3, rot, NIT - 1, tid);
        }
        #pragma unroll
        for (int q = 0; q < 2; ++q) {
            const int bbA = ((2 * s + q) & 3) * 512;
            const int bbB = 2048 + ((2 * s + q) & 3) * 1024;
            #pragma unroll
            for (int sub = 0; sub < 2; ++sub) {
                const int kq = sub * 4 + (lane >> 4);
                bf16x8 a[2], b[4];
                #pragma unroll
                for (int mI = 0; mI < 2; ++mI)
                    a[mI] = smem[bbA + kq * 64 + wr + mI * 16 + (lane & 15)];
                #pragma unroll
                for (int g = 0; g < 4; ++g)
                    b[g] = smem[bbB + kq * 128 + g * 32 + ws * 16 + (lane & 15)];
                #pragma unroll
                for (int mI = 0; mI < 2; ++mI)
                    #pragma unroll
                    for (int g = 0; g < 4; ++g)
                        acc[mI][g] = __builtin_amdgcn_mfma_f32_16x16x32_bf16(a[mI], b[g], acc[mI][g], 0, 0, 0);
            }
        }
    }
}

// ---- LSTM epilogue: gates, m_reg update, stage h (bf16) into LDS ----
// staging tile [64 rows][32 cols] bf16, row stride 80 B.
__device__ __forceinline__ void epi_stage(const f32x4 (&acc)[2][4], float (&m_reg)[8],
    float bu, float bf_, float bo, float bc,
    char* stg, int wrL, int colq)
{
    #pragma unroll
    for (int mI = 0; mI < 2; ++mI) {
        #pragma unroll
        for (int r = 0; r < 4; ++r) {
            const int rowL = wrL + mI * 16 + r;   // local row 0..63
            const float gu = sig_(acc[mI][0][r] + bu);
            const float gf = sig_(acc[mI][1][r] + bf_);
            const float go = sig_(acc[mI][2][r] + bo);
            const float gc = tanh_(acc[mI][3][r] + bc);
            float& m = m_reg[mI * 4 + r];
            m = gf * m + gu * gc;
            ((__bf16*)(stg + rowL * 80))[colq] = (__bf16)tanh_(go * m);
        }
    }
}

// coalesced flush: 64x32 bf16 tile = 256 chunks -> 1 store/thread.
__device__ __forceinline__ void flush_h(char* stg, __bf16* hbase, int r0,
                                        int scolBase, int tid)
{
    const int rowL = tid >> 2;
    const int off  = tid & 3;
    bf16x8 v = *(bf16x8*)(stg + rowL * 80 + off * 16);
    store16_dev(hbase + (size_t)(r0 + rowL) * NS + scolBase + off * 8, v);
}

// final-step epilogue: stage h,m f32 in (idle) pipeline LDS, coalesced out.
__device__ __forceinline__ void epi_last(const f32x4 (&acc)[2][4], float (&m_reg)[8],
    float bu, float bf_, float bo, float bc,
    char* hs, char* ms, int wrL, int colq)
{
    #pragma unroll
    for (int mI = 0; mI < 2; ++mI) {
        #pragma unroll
        for (int r = 0; r < 4; ++r) {
            const int rowL = wrL + mI * 16 + r;
            const float gu = sig_(acc[mI][0][r] + bu);
            const float gf = sig_(acc[mI][1][r] + bf_);
            const float go = sig_(acc[mI][2][r] + bo);
            const float gc = tanh_(acc[mI][3][r] + bc);
            float& m = m_reg[mI * 4 + r];
            m = gf * m + gu * gc;
            ((float*)(hs + rowL * 144))[colq] = tanh_(go * m);
            ((float*)(ms + rowL * 144))[colq] = m;
        }
    }
}

// 256 blocks x 256 threads, ~101 KB LDS -> exactly 1 block/CU (hardware
// cannot co-locate two), so all 256 blocks co-resident: spin-safe.
__global__ __launch_bounds__(256, 1)
void lstm_persistent(Params p)
{
    __shared__ bf16x8 smem[6464];   // 96KB pipeline (A 4x512, B 4x1024) + 5KB staging
    char* stg = (char*)&smem[6144];

    const int tid  = threadIdx.x;
    const int lane = tid & 63;
    const int wv   = tid >> 6;
    const int wr   = (wv >> 1) * 32;     // wave row-band (2 frags of 16)
    const int ws   = wv & 1;             // wave col-strip (16 cols per gate)

    // ---- XCD-aware work map (dispatch assigns bid -> XCD bid%8) ----
    // Each XCD: one dof x 4 rt-groups x 8 strips = 32 blocks; weights 3MB/XCD.
    const int xcd   = blockIdx.x & 7;
    const int local = blockIdx.x >> 3;            // 0..31
    const int dof   = xcd & 3;
    const int rt    = (xcd >> 2) * 4 + (local >> 3);   // 0..7 (64-row tiles)
    const int c0    = (local & 7) * 32;
    const int r0    = rt * 64;
    const int grp   = rt * 4 + dof;               // 0..31

    const int colq = ws * 16 + (lane & 15);       // 0..31 (block-local col)
    const int scol = dof * ND + c0 + colq;
    const int scolBase = dof * ND + c0;
    const int wrL  = wr + (lane >> 4) * 4;        // local row base 0..60

    const int rowB = tid & 127;
    const int npT  = dof * 1024 + (rowB >> 5) * 256 + c0 + (rowB & 31);
    const __bf16* wrow1 = p.wT1 + (size_t)npT * 512;
    const __bf16* wrow2 = p.wT2 + (size_t)npT * 1024;

    const float b1u = p.b1u[scol], b1f = p.b1f[scol], b1o = p.b1o[scol], b1c = p.b1c[scol];
    const float b2u = p.b2u[scol], b2f = p.b2f[scol], b2o = p.b2o[scol], b2c = p.b2c[scol];

    float m_reg[8];
    #pragma unroll
    for (int i = 0; i < 8; ++i) m_reg[i] = 0.f;

    Bar* bar32A = &p.bars[rt];
    Bar* bar8A  = &p.bars[8 + grp];
    Bar* bar8B  = &p.bars[40 + grp];
    const int rot2 = dof * 4;   // phase-2 K rotation: own-dof h1 cols first

    auto slot = [&](int i) -> __bf16* { return p.ring + ((size_t)i << 19); };

    // kernel-start prologue: pairs 0,1 of t=0 phase-1 (B,B then A,A; all x/w)
    {
        const __bf16* ax0 = p.xbf + ((size_t)(dof * NT) * NB + r0) * ND;
        issueB(smem, wrow1, 0, 0, 7, tid);
        issueB(smem, wrow1, 1, 0, 7, tid);
        issueA<4>(smem, ax0, nullptr, 0, 0, 7, tid);
        issueA<4>(smem, ax0, nullptr, 1, 0, 7, tid);
    }

    #pragma unroll 1
    for (int t = 0; t < NT; ++t) {
        const __bf16* ax  = p.xbf + ((size_t)(dof * NT + t) * NB + r0) * ND;
        const __bf16* ah1 = (t == 0 ? p.hInit : slot(2 * t - 1)) + (size_t)r0 * NS + dof * ND;
        __bf16* h1out = slot(2 * t);
        const __bf16* ah2 = slot(2 * t) + (size_t)r0 * NS;
        __bf16* h2out = slot(2 * t + 1);

        // ---------- phase 1: per-dof cell, K=512 = [x_t | h_own] ----------
        f32x4 acc[2][4];
        #pragma unroll
        for (int mI = 0; mI < 2; ++mI)
            #pragma unroll
            for (int g = 0; g < 4; ++g) acc[mI][g] = (f32x4){0.f, 0.f, 0.f, 0.f};

        gemm_seg<8, 4>(smem, ax, ah1, wrow1, 0, bar8B, (unsigned)t,
                       acc, lane, wr, ws, tid);

        // ---- transition A ----
        epi_stage(acc, m_reg, b1u, b1f, b1o, b1c, stg, wrL, colq);
        block_bar();                      // staging visible block-wide
        flush_h(stg, h1out, r0, scolBase, tid);      // 1 coalesced store (oldest)
        issueB(smem, wrow2, 0, rot2, 15, tid);       // 8 B2-prologue loads
        issueB(smem, wrow2, 1, rot2, 15, tid);
        waitv8();                         // retires the store, loads in flight
        block_bar();
        if (tid == 0) {
            arrive_only(bar8A, 8, (unsigned)(t + 1));
            arrive_only(bar32A, 32, (unsigned)(t + 1));
            poll_only(bar8A, (unsigned)(t + 1));
        }
        block_bar();
        issueA<0>(smem, nullptr, ah2, 0, rot2, 15, tid);
        issueA<0>(smem, nullptr, ah2, 1, rot2, 15, tid);

        // ---------- phase 2: grid coupling, K=1024 (own dof first) ----------
        #pragma unroll
        for (int mI = 0; mI < 2; ++mI)
            #pragma unroll
            for (int g = 0; g < 4; ++g) acc[mI][g] = (f32x4){0.f, 0.f, 0.f, 0.f};

        gemm_seg<16, 0>(smem, nullptr, ah2, wrow2, rot2, bar32A, (unsigned)(t + 1),
                        acc, lane, wr, ws, tid);

        if (t + 1 < NT) {
            // ---- transition B ----
            epi_stage(acc, m_reg, b2u, b2f, b2o, b2c, stg, wrL, colq);
            block_bar();
            flush_h(stg, h2out, r0, scolBase, tid);  // 1 store (oldest)
            const __bf16* axn = p.xbf + ((size_t)(dof * NT + t + 1) * NB + r0) * ND;
            issueB(smem, wrow1, 0, 0, 7, tid);       // next ph1 pairs 0,1 (x/w only)
            issueB(smem, wrow1, 1, 0, 7, tid);
            issueA<4>(smem, axn, nullptr, 0, 0, 7, tid);
            issueA<4>(smem, axn, nullptr, 1, 0, 7, tid);
            waitv12();                    // retires the store; 12 loads in flight
            block_bar();
            if (tid == 0) arrive_only(bar8B, 8, (unsigned)(t + 1));
            // next phase-1 gates on bar8B at its s==1
        } else {
            // ---- final epilogue: coalesced f32 h+m into d_out ----
            block_bar();                  // pipeline LDS now reusable
            char* hs = (char*)smem;           // [64][144B] f32 h
            char* ms = (char*)smem + 9216;    // [64][144B] f32 m
            epi_last(acc, m_reg, b2u, b2f, b2o, b2c, hs, ms, wrL, colq);
            block_bar();
            #pragma unroll
            for (int k = 0; k < 2; ++k) {
                const int c = tid + 256 * k;      // 0..511
                const int rowL = c >> 3;          // 0..63
                const int off  = c & 7;           // 8 x 16B per 128B row
                const size_t gi = ((size_t)dof * NB + r0 + rowL) * ND + c0 + off * 4;
                *(f32x4*)(p.out + gi) = *(f32x4*)(hs + rowL * 144 + off * 16);
                *(f32x4*)(p.out + (size_t)NDOF * NB * ND + gi) = *(f32x4*)(ms + rowL * 144 + off * 16);
            }
        }
    }
}

// ---- one-time prep: x[d][b][t][:] fp32 -> xbf[d][t][b][:] bf16 ----
__global__ __launch_bounds__(256)
void convert_x(const float* __restrict__ x, __bf16* __restrict__ xbf)
{
    const int id  = blockIdx.x * 256 + threadIdx.x;
    const int d0  = (id & 31) * 8;
    const int t   = (id >> 5) & 63;
    const int b   = (id >> 11) & 511;
    const int dof = id >> 20;
    const float* s = x + (((size_t)dof * NB + b) * NT + t) * ND + d0;
    const float4 v0 = *(const float4*)s;
    const float4 v1 = *(const float4*)(s + 4);
    bf16x8 o;
    o[0] = (__bf16)v0.x; o[1] = (__bf16)v0.y; o[2] = (__bf16)v0.z; o[3] = (__bf16)v0.w;
    o[4] = (__bf16)v1.x; o[5] = (__bf16)v1.y; o[6] = (__bf16)v1.z; o[7] = (__bf16)v1.w;
    *(bf16x8*)(xbf + (((size_t)dof * NT + t) * NB + b) * ND + d0) = o;
}

// ---- one-time prep: weights -> bf16 wT[n'][k], n' = dof*1024 + g*256 + col ----
__global__ __launch_bounds__(256)
void transpose_weights(const float* __restrict__ wu, const float* __restrict__ wf,
                       const float* __restrict__ wo, const float* __restrict__ wcp,
                       const float* __restrict__ gwu, const float* __restrict__ gwf,
                       const float* __restrict__ gwo, const float* __restrict__ gwc,
                       __bf16* __restrict__ wT1, __bf16* __restrict__ wT2)
{
    int id = blockIdx.x * 256 + threadIdx.x;
    const int C1 = 4096 * 64;
    int K, np, kc;
    const float *s0, *s1, *s2, *s3;
    __bf16* dst;
    if (id < C1) { K = 512;  np = id & 4095; kc = id >> 12; dst = wT1; s0 = wu;  s1 = wf;  s2 = wo;  s3 = wcp; }
    else { id -= C1; K = 1024; np = id & 4095; kc = id >> 12; dst = wT2; s0 = gwu; s1 = gwf; s2 = gwo; s3 = gwc; }
    const int dof = np >> 10, q = np & 1023, g = q >> 8, col = q & 255;
    const float* w = ((g == 0) ? s0 : (g == 1) ? s1 : (g == 2) ? s2 : s3)
                     + ((size_t)dof * K + kc * 8) * ND + col;
    bf16x8 o;
    #pragma unroll
    for (int j = 0; j < 8; ++j) o[j] = (__bf16)w[j * ND];
    *(bf16x8*)(dst + (size_t)np * K + kc * 8) = o;
}

extern "C" void kernel_launch(void* const* d_in, const int* in_sizes, int n_in,
                              void* d_out, int out_size, void* d_ws, size_t ws_size,
                              hipStream_t stream)
{
    const float* x   = (const float*)d_in[0];
    const float* wu  = (const float*)d_in[1];
    const float* wf  = (const float*)d_in[2];
    const float* wo  = (const float*)d_in[3];
    const float* wc  = (const float*)d_in[4];

    char* ws = (char*)d_ws;
    __bf16* wT1  = (__bf16*)ws;                        //   4 MB  [4096][512]
    __bf16* wT2  = (__bf16*)(ws + (4u  << 20));        //   8 MB  [4096][1024]
    __bf16* xbf  = (__bf16*)(ws + (12u << 20));        //  64 MB  [4][64][512][256]
    __bf16* hIn  = (__bf16*)(ws + (76u << 20));        //   1 MB  zeros
    Bar*    bars = (Bar*)  (ws + (78u << 20));         //   8 KB
    __bf16* ring = (__bf16*)(ws + (80u << 20));        // 128 MB  [NT*2][512][1024]

    convert_x<<<16384, 256, 0, stream>>>(x, xbf);
    transpose_weights<<<3072, 256, 0, stream>>>(
        wu, wf, wo, wc,
        (const float*)d_in[9], (const float*)d_in[10],
        (const float*)d_in[11], (const float*)d_in[12], wT1, wT2);
    // zero hInit + bars each call (deterministic across replays)
    hipMemsetAsync(ws + (76u << 20), 0, (2u << 20) + 8192, stream);

    Params p;
    p.xbf = xbf; p.wT1 = wT1; p.wT2 = wT2;
    p.b1u = (const float*)d_in[5];  p.b1f = (const float*)d_in[6];
    p.b1o = (const float*)d_in[7];  p.b1c = (const float*)d_in[8];
    p.b2u = (const float*)d_in[13]; p.b2f = (const float*)d_in[14];
    p.b2o = (const float*)d_in[15]; p.b2c = (const float*)d_in[16];
    p.hInit = hIn; p.ring = ring; p.out = (float*)d_out; p.bars = bars;

    lstm_persistent<<<dim3(GRID), dim3(256), 0, stream>>>(p);
}

// Round 14
// 1568.439 us; speedup vs baseline: 1.4114x; 1.0364x over previous
//
#include <hip/hip_runtime.h>
#include <math.h>

#define NDOF 4
#define NB   512
#define NT   64
#define ND   256
#define NS   1024           // NDOF*ND

// 256 blocks = 8 rt (64-row tiles) x 32 nt (4 gates x 32 cols), XCD-mapped.
#define GRID 256

typedef __attribute__((ext_vector_type(8))) __bf16 bf16x8;
typedef __attribute__((ext_vector_type(4))) float  f32x4;

__device__ __forceinline__ void gll16(const void* g, void* l) {
    __builtin_amdgcn_global_load_lds(
        (const __attribute__((address_space(1))) unsigned int*)g,
        (__attribute__((address_space(3))) unsigned int*)l, 16, 0, 0);
}

__device__ __forceinline__ float sig_(float x) { return 1.0f / (1.0f + __expf(-x)); }
__device__ __forceinline__ float tanh_(float x) {
    float e = __expf(-2.0f * fabsf(x));
    float t = (1.0f - e) / (1.0f + e);
    return copysignf(t, x);
}

// coalesced coherent store: 16B write-through to MALL
__device__ __forceinline__ void store16_dev(__bf16* p, bf16x8 v) {
    asm volatile("global_store_dwordx4 %0, %1, off sc0 sc1" :: "v"(p), "v"(v) : "memory");
}
// flag publish: plain coherent store (no RMW -> no MALL line contention)
__device__ __forceinline__ void store_flag(unsigned* p, unsigned v) {
    asm volatile("global_store_dword %0, %1, off sc0 sc1" :: "v"(p), "v"(v) : "memory");
}
// coherent flag read (per-lane; coalesces group reads into one MALL access)
__device__ __forceinline__ unsigned flag_load(const unsigned* p) {
    unsigned v;
    asm volatile("global_load_dword %0, %1, off sc0 sc1\n\ts_waitcnt vmcnt(0)"
                 : "=v"(v) : "v"(p) : "memory");
    return v;
}

__device__ __forceinline__ void waitv0() {
    asm volatile("s_waitcnt vmcnt(0)" ::: "memory");
    __builtin_amdgcn_sched_barrier(0);
}
__device__ __forceinline__ void waitv8() {
    asm volatile("s_waitcnt vmcnt(8)" ::: "memory");
    __builtin_amdgcn_sched_barrier(0);
}
__device__ __forceinline__ void waitv12() {
    asm volatile("s_waitcnt vmcnt(12)" ::: "memory");
    __builtin_amdgcn_sched_barrier(0);
}

// raw block barrier: does NOT drain vmcnt (loads stay in flight across it).
__device__ __forceinline__ void block_bar() {
    __builtin_amdgcn_sched_barrier(0);
    asm volatile("s_waitcnt lgkmcnt(0)\n\ts_barrier" ::: "memory");
    __builtin_amdgcn_sched_barrier(0);
}

// ---- wave-wide flag-array gate: lanes 0..nf-1 each load one flag word;
// ONE coalesced MALL round trip checks the whole group. No writes -> the
// flag lines are never owned by pollers (contrast: r13's RMW arrivals).
__device__ __forceinline__ void poll_flags(const unsigned* f, int nf, unsigned e, int lane) {
    unsigned spins = 0;
    for (;;) {
        unsigned v = e;
        if (lane < nf) v = flag_load(f + lane);
        if (__all(v >= e)) break;
        __builtin_amdgcn_s_sleep(1);
        if (++spins > (1u << 15)) break;   // failsafe: fail loud, never hang
    }
}

struct Params {
    const __bf16* xbf;
    const __bf16* wT1;
    const __bf16* wT2;
    const float *b1u, *b1f, *b1o, *b1c;
    const float *b2u, *b2f, *b2o, *b2c;
    const __bf16* hInit;   // 1 MB zeros [512][1024]
    __bf16* ring;          // [NT*2] slots of [512][1024] bf16 (1 MB each)
    float*  out;
    unsigned* flags;       // [0..255]=flagP1[rt*32+dof*8+strip]; [256..511]=flagP2
};

// ---- pair staging. rot permutes the K order (pair p -> k ((p+rot)&mask)*64).
// LDS 16B-chunk units: A 4-deep [0,2048) (512/buf), B 4-deep [2048,6144) (1024/buf).
__device__ __forceinline__ void issueB(bf16x8* smem, const __bf16* wrow,
                                       int pair, int rot, int mask, int tid) {
    const int rowB = tid & 127;
    const int kgb  = (tid >> 7) & 1;
    const int bb = 2048 + (pair & 3) * 1024;
    const int k0 = ((pair + rot) & mask) * 64;
    #pragma unroll
    for (int i = 0; i < 4; ++i) {
        const int kg = kgb + 2 * i;
        gll16(wrow + k0 + kg * 8, &smem[bb + kg * 128 + rowB]);
    }
}
template<int XIT>
__device__ __forceinline__ void issueA(bf16x8* smem, const __bf16* ax,
                                       const __bf16* ah, int pair, int rot, int mask,
                                       int tid) {
    const int rowA = tid & 63;
    const int kga  = tid >> 6;            // 0..3
    const int bb = (pair & 3) * 512;
    const __bf16* base;
    if (XIT > 0 && pair < XIT) base = ax + (size_t)rowA * ND + pair * 64;   // x (rot=0)
    else base = ah + (size_t)rowA * NS + (((pair + rot) & mask) * 64 - XIT * 64);
    #pragma unroll
    for (int i = 0; i < 2; ++i) {
        const int kg = kga + 4 * i;
        gll16(base + kg * 8, &smem[bb + kg * 64 + rowA]);
    }
}

// ---- GEMM core: 2 pairs/segment, rolled loop. Pairs 0,1 pre-issued.
// gateF (if set): wave 0 polls gateN flags >= gateE at s==1, before the
// first gated pair issue -- hides the group sync under pairs 0-3's compute.
template<int NIT, int XIT>
__device__ __forceinline__ void gemm_seg(bf16x8* smem,
    const __bf16* ax, const __bf16* ah, const __bf16* wrow, int rot,
    const unsigned* gateF, int gateN, unsigned gateE,
    f32x4 (&acc)[2][4], int lane, int wr, int ws, int tid)
{
    constexpr int NSEG = NIT / 2;
    #pragma unroll 1
    for (int s = 0; s < NSEG; ++s) {
        waitv0();
        block_bar();
        if (s == 1 && gateF != nullptr) {
            if (tid < 64) poll_flags(gateF, gateN, gateE, lane);
            block_bar();
        }
        if (s + 1 < NSEG) {
            issueB(smem, wrow, 2 * s + 2, rot, NIT - 1, tid);
            issueB(smem, wrow, 2 * s + 3, rot, NIT - 1, tid);
            issueA<XIT>(smem, ax, ah, 2 * s + 2, rot, NIT - 1, tid);
            issueA<XIT>(smem, ax, ah, 2 * s + 3, rot, NIT - 1, tid);
        }
        #pragma unroll
        for (int q = 0; q < 2; ++q) {
            const int bbA = ((2 * s + q) & 3) * 512;
            const int bbB = 2048 + ((2 * s + q) & 3) * 1024;
            #pragma unroll
            for (int sub = 0; sub < 2; ++sub) {
                const int kq = sub * 4 + (lane >> 4);
                bf16x8 a[2], b[4];
                #pragma unroll
                for (int mI = 0; mI < 2; ++mI)
                    a[mI] = smem[bbA + kq * 64 + wr + mI * 16 + (lane & 15)];
                #pragma unroll
                for (int g = 0; g < 4; ++g)
                    b[g] = smem[bbB + kq * 128 + g * 32 + ws * 16 + (lane & 15)];
                #pragma unroll
                for (int mI = 0; mI < 2; ++mI)
                    #pragma unroll
                    for (int g = 0; g < 4; ++g)
                        acc[mI][g] = __builtin_amdgcn_mfma_f32_16x16x32_bf16(a[mI], b[g], acc[mI][g], 0, 0, 0);
            }
        }
    }
}

// ---- LSTM epilogue: gates, m_reg update, stage h (bf16) into LDS ----
__device__ __forceinline__ void epi_stage(const f32x4 (&acc)[2][4], float (&m_reg)[8],
    float bu, float bf_, float bo, float bc,
    char* stg, int wrL, int colq)
{
    #pragma unroll
    for (int mI = 0; mI < 2; ++mI) {
        #pragma unroll
        for (int r = 0; r < 4; ++r) {
            const int rowL = wrL + mI * 16 + r;   // local row 0..63
            const float gu = sig_(acc[mI][0][r] + bu);
            const float gf = sig_(acc[mI][1][r] + bf_);
            const float go = sig_(acc[mI][2][r] + bo);
            const float gc = tanh_(acc[mI][3][r] + bc);
            float& m = m_reg[mI * 4 + r];
            m = gf * m + gu * gc;
            ((__bf16*)(stg + rowL * 80))[colq] = (__bf16)tanh_(go * m);
        }
    }
}

// coalesced flush: 64x32 bf16 tile = 256 chunks -> 1 store/thread.
__device__ __forceinline__ void flush_h(char* stg, __bf16* hbase, int r0,
                                        int scolBase, int tid)
{
    const int rowL = tid >> 2;
    const int off  = tid & 3;
    bf16x8 v = *(bf16x8*)(stg + rowL * 80 + off * 16);
    store16_dev(hbase + (size_t)(r0 + rowL) * NS + scolBase + off * 8, v);
}

// final-step epilogue: stage h,m f32 in (idle) pipeline LDS, coalesced out.
__device__ __forceinline__ void epi_last(const f32x4 (&acc)[2][4], float (&m_reg)[8],
    float bu, float bf_, float bo, float bc,
    char* hs, char* ms, int wrL, int colq)
{
    #pragma unroll
    for (int mI = 0; mI < 2; ++mI) {
        #pragma unroll
        for (int r = 0; r < 4; ++r) {
            const int rowL = wrL + mI * 16 + r;
            const float gu = sig_(acc[mI][0][r] + bu);
            const float gf = sig_(acc[mI][1][r] + bf_);
            const float go = sig_(acc[mI][2][r] + bo);
            const float gc = tanh_(acc[mI][3][r] + bc);
            float& m = m_reg[mI * 4 + r];
            m = gf * m + gu * gc;
            ((float*)(hs + rowL * 144))[colq] = tanh_(go * m);
            ((float*)(ms + rowL * 144))[colq] = m;
        }
    }
}

// 256 blocks x 256 threads, ~101 KB LDS -> exactly 1 block/CU: all blocks
// co-resident, spin-safe.
__global__ __launch_bounds__(256, 1)
void lstm_persistent(Params p)
{
    __shared__ bf16x8 smem[6464];   // 96KB pipeline (A 4x512, B 4x1024) + 5KB staging
    char* stg = (char*)&smem[6144];

    const int tid  = threadIdx.x;
    const int lane = tid & 63;
    const int wv   = tid >> 6;
    const int wr   = (wv >> 1) * 32;     // wave row-band (2 frags of 16)
    const int ws   = wv & 1;             // wave col-strip (16 cols per gate)

    // ---- XCD-aware work map (dispatch assigns bid -> XCD bid%8) ----
    const int xcd   = blockIdx.x & 7;
    const int local = blockIdx.x >> 3;            // 0..31
    const int dof   = xcd & 3;
    const int rt    = (xcd >> 2) * 4 + (local >> 3);   // 0..7 (64-row tiles)
    const int strip = local & 7;
    const int c0    = strip * 32;
    const int r0    = rt * 64;
    const int grp   = rt * 4 + dof;               // 0..31

    const int colq = ws * 16 + (lane & 15);       // 0..31 (block-local col)
    const int scol = dof * ND + c0 + colq;
    const int scolBase = dof * ND + c0;
    const int wrL  = wr + (lane >> 4) * 4;        // local row base 0..60

    const int rowB = tid & 127;
    const int npT  = dof * 1024 + (rowB >> 5) * 256 + c0 + (rowB & 31);
    const __bf16* wrow1 = p.wT1 + (size_t)npT * 512;
    const __bf16* wrow2 = p.wT2 + (size_t)npT * 1024;

    const float b1u = p.b1u[scol], b1f = p.b1f[scol], b1o = p.b1o[scol], b1c = p.b1c[scol];
    const float b2u = p.b2u[scol], b2f = p.b2f[scol], b2o = p.b2o[scol], b2c = p.b2c[scol];

    float m_reg[8];
    #pragma unroll
    for (int i = 0; i < 8; ++i) m_reg[i] = 0.f;

    // flag bases: P1[grp*8+strip] set after ph1 flush; P2 after ph2 flush.
    unsigned* fP1own = p.flags + grp * 8;          // own-dof group (8)
    unsigned* fP1rt  = p.flags + rt * 32;          // all 4 dofs of rt (32)
    unsigned* fP2own = p.flags + 256 + grp * 8;    // own-dof group (8)
    unsigned* myP1   = p.flags + grp * 8 + strip;
    unsigned* myP2   = p.flags + 256 + grp * 8 + strip;
    const int rot2 = dof * 4;   // phase-2 K rotation: own-dof h1 cols first

    auto slot = [&](int i) -> __bf16* { return p.ring + ((size_t)i << 19); };

    // kernel-start prologue: pairs 0,1 of t=0 phase-1 (B,B then A,A; all x/w)
    {
        const __bf16* ax0 = p.xbf + ((size_t)(dof * NT) * NB + r0) * ND;
        issueB(smem, wrow1, 0, 0, 7, tid);
        issueB(smem, wrow1, 1, 0, 7, tid);
        issueA<4>(smem, ax0, nullptr, 0, 0, 7, tid);
        issueA<4>(smem, ax0, nullptr, 1, 0, 7, tid);
    }

    #pragma unroll 1
    for (int t = 0; t < NT; ++t) {
        const __bf16* ax  = p.xbf + ((size_t)(dof * NT + t) * NB + r0) * ND;
        const __bf16* ah1 = (t == 0 ? p.hInit : slot(2 * t - 1)) + (size_t)r0 * NS + dof * ND;
        __bf16* h1out = slot(2 * t);
        const __bf16* ah2 = slot(2 * t) + (size_t)r0 * NS;
        __bf16* h2out = slot(2 * t + 1);

        // ---------- phase 1: per-dof cell, K=512 = [x_t | h_own] ----------
        // h pairs (4-7) gated at s==1 on own-dof flagP2 >= t.
        f32x4 acc[2][4];
        #pragma unroll
        for (int mI = 0; mI < 2; ++mI)
            #pragma unroll
            for (int g = 0; g < 4; ++g) acc[mI][g] = (f32x4){0.f, 0.f, 0.f, 0.f};

        gemm_seg<8, 4>(smem, ax, ah1, wrow1, 0, fP2own, 8, (unsigned)t,
                       acc, lane, wr, ws, tid);

        // ---- transition A ----
        epi_stage(acc, m_reg, b1u, b1f, b1o, b1c, stg, wrL, colq);
        block_bar();                      // staging visible block-wide
        flush_h(stg, h1out, r0, scolBase, tid);   // 1 coalesced store (oldest)
        issueB(smem, wrow2, 0, rot2, 15, tid);    // 8 B2-prologue loads
        issueB(smem, wrow2, 1, rot2, 15, tid);
        waitv8();                         // retires the store, loads in flight
        block_bar();                      // ALL threads' h stores retired
        if (tid == 0) store_flag(myP1, (unsigned)(t + 1));   // publish (no RMW)
        if (tid < 64) poll_flags(fP1own, 8, (unsigned)(t + 1), lane);  // own-dof gate
        block_bar();
        issueA<0>(smem, nullptr, ah2, 0, rot2, 15, tid);
        issueA<0>(smem, nullptr, ah2, 1, rot2, 15, tid);

        // ---------- phase 2: grid coupling, K=1024 (own dof first) ----------
        // other-dof pairs (4+) gated at s==1 on all 32 flagP1 >= t+1.
        #pragma unroll
        for (int mI = 0; mI < 2; ++mI)
            #pragma unroll
            for (int g = 0; g < 4; ++g) acc[mI][g] = (f32x4){0.f, 0.f, 0.f, 0.f};

        gemm_seg<16, 0>(smem, nullptr, ah2, wrow2, rot2, fP1rt, 32, (unsigned)(t + 1),
                        acc, lane, wr, ws, tid);

        if (t + 1 < NT) {
            // ---- transition B ----
            epi_stage(acc, m_reg, b2u, b2f, b2o, b2c, stg, wrL, colq);
            block_bar();
            flush_h(stg, h2out, r0, scolBase, tid);  // 1 store (oldest)
            const __bf16* axn = p.xbf + ((size_t)(dof * NT + t + 1) * NB + r0) * ND;
            issueB(smem, wrow1, 0, 0, 7, tid);       // next ph1 pairs 0,1 (x/w only)
            issueB(smem, wrow1, 1, 0, 7, tid);
            issueA<4>(smem, axn, nullptr, 0, 0, 7, tid);
            issueA<4>(smem, axn, nullptr, 1, 0, 7, tid);
            waitv12();                    // retires the store; 12 loads in flight
            block_bar();                  // all h2 stores retired
            if (tid == 0) store_flag(myP2, (unsigned)(t + 1));   // publish
            // next phase-1 gates on own-dof flagP2 at its s==1
        } else {
            // ---- final epilogue: coalesced f32 h+m into d_out ----
            block_bar();                  // pipeline LDS now reusable
            char* hs = (char*)smem;           // [64][144B] f32 h
            char* ms = (char*)smem + 9216;    // [64][144B] f32 m
            epi_last(acc, m_reg, b2u, b2f, b2o, b2c, hs, ms, wrL, colq);
            block_bar();
            #pragma unroll
            for (int k = 0; k < 2; ++k) {
                const int c = tid + 256 * k;      // 0..511
                const int rowL = c >> 3;          // 0..63
                const int off  = c & 7;           // 8 x 16B per 128B row
                const size_t gi = ((size_t)dof * NB + r0 + rowL) * ND + c0 + off * 4;
                *(f32x4*)(p.out + gi) = *(f32x4*)(hs + rowL * 144 + off * 16);
                *(f32x4*)(p.out + (size_t)NDOF * NB * ND + gi) = *(f32x4*)(ms + rowL * 144 + off * 16);
            }
        }
    }
}

// ---- one-time prep: x[d][b][t][:] fp32 -> xbf[d][t][b][:] bf16 ----
__global__ __launch_bounds__(256)
void convert_x(const float* __restrict__ x, __bf16* __restrict__ xbf)
{
    const int id  = blockIdx.x * 256 + threadIdx.x;
    const int d0  = (id & 31) * 8;
    const int t   = (id >> 5) & 63;
    const int b   = (id >> 11) & 511;
    const int dof = id >> 20;
    const float* s = x + (((size_t)dof * NB + b) * NT + t) * ND + d0;
    const float4 v0 = *(const float4*)s;
    const float4 v1 = *(const float4*)(s + 4);
    bf16x8 o;
    o[0] = (__bf16)v0.x; o[1] = (__bf16)v0.y; o[2] = (__bf16)v0.z; o[3] = (__bf16)v0.w;
    o[4] = (__bf16)v1.x; o[5] = (__bf16)v1.y; o[6] = (__bf16)v1.z; o[7] = (__bf16)v1.w;
    *(bf16x8*)(xbf + (((size_t)dof * NT + t) * NB + b) * ND + d0) = o;
}

// ---- one-time prep: weights -> bf16 wT[n'][k], n' = dof*1024 + g*256 + col ----
__global__ __launch_bounds__(256)
void transpose_weights(const float* __restrict__ wu, const float* __restrict__ wf,
                       const float* __restrict__ wo, const float* __restrict__ wcp,
                       const float* __restrict__ gwu, const float* __restrict__ gwf,
                       const float* __restrict__ gwo, const float* __restrict__ gwc,
                       __bf16* __restrict__ wT1, __bf16* __restrict__ wT2)
{
    int id = blockIdx.x * 256 + threadIdx.x;
    const int C1 = 4096 * 64;
    int K, np, kc;
    const float *s0, *s1, *s2, *s3;
    __bf16* dst;
    if (id < C1) { K = 512;  np = id & 4095; kc = id >> 12; dst = wT1; s0 = wu;  s1 = wf;  s2 = wo;  s3 = wcp; }
    else { id -= C1; K = 1024; np = id & 4095; kc = id >> 12; dst = wT2; s0 = gwu; s1 = gwf; s2 = gwo; s3 = gwc; }
    const int dof = np >> 10, q = np & 1023, g = q >> 8, col = q & 255;
    const float* w = ((g == 0) ? s0 : (g == 1) ? s1 : (g == 2) ? s2 : s3)
                     + ((size_t)dof * K + kc * 8) * ND + col;
    bf16x8 o;
    #pragma unroll
    for (int j = 0; j < 8; ++j) o[j] = (__bf16)w[j * ND];
    *(bf16x8*)(dst + (size_t)np * K + kc * 8) = o;
}

extern "C" void kernel_launch(void* const* d_in, const int* in_sizes, int n_in,
                              void* d_out, int out_size, void* d_ws, size_t ws_size,
                              hipStream_t stream)
{
    const float* x   = (const float*)d_in[0];
    const float* wu  = (const float*)d_in[1];
    const float* wf  = (const float*)d_in[2];
    const float* wo  = (const float*)d_in[3];
    const float* wc  = (const float*)d_in[4];

    char* ws = (char*)d_ws;
    __bf16* wT1  = (__bf16*)ws;                        //   4 MB  [4096][512]
    __bf16* wT2  = (__bf16*)(ws + (4u  << 20));        //   8 MB  [4096][1024]
    __bf16* xbf  = (__bf16*)(ws + (12u << 20));        //  64 MB  [4][64][512][256]
    __bf16* hIn  = (__bf16*)(ws + (76u << 20));        //   1 MB  zeros
    unsigned* flags = (unsigned*)(ws + (78u << 20));   //   2 KB
    __bf16* ring = (__bf16*)(ws + (80u << 20));        // 128 MB  [NT*2][512][1024]

    convert_x<<<16384, 256, 0, stream>>>(x, xbf);
    transpose_weights<<<3072, 256, 0, stream>>>(
        wu, wf, wo, wc,
        (const float*)d_in[9], (const float*)d_in[10],
        (const float*)d_in[11], (const float*)d_in[12], wT1, wT2);
    // zero hInit + flags each call (deterministic across replays)
    hipMemsetAsync(ws + (76u << 20), 0, (2u << 20) + 8192, stream);

    Params p;
    p.xbf = xbf; p.wT1 = wT1; p.wT2 = wT2;
    p.b1u = (const float*)d_in[5];  p.b1f = (const float*)d_in[6];
    p.b1o = (const float*)d_in[7];  p.b1c = (const float*)d_in[8];
    p.b2u = (const float*)d_in[13]; p.b2f = (const float*)d_in[14];
    p.b2o = (const float*)d_in[15]; p.b2c = (const float*)d_in[16];
    p.hInit = hIn; p.ring = ring; p.out = (float*)d_out; p.flags = flags;

    lstm_persistent<<<dim3(GRID), dim3(256), 0, stream>>>(p);
}